// Round 7
// baseline (192.936 us; speedup 1.0000x reference)
//
#include <hip/hip_runtime.h>
#include <hip/hip_bf16.h>
#include <cstdint>

typedef __bf16 bf16_t;
typedef __bf16 bf16x8 __attribute__((ext_vector_type(8)));
typedef __bf16 bf16x4 __attribute__((ext_vector_type(4)));
typedef float floatx4 __attribute__((ext_vector_type(4)));
typedef float floatx16 __attribute__((ext_vector_type(16)));
typedef uint32_t u32x4 __attribute__((ext_vector_type(4)));

typedef __attribute__((address_space(3))) uint32_t lds_u32_t;
typedef const __attribute__((address_space(1))) uint32_t g_u32_t;

#define MFMA_BF16(a, b, c) __builtin_amdgcn_mfma_f32_16x16x32_bf16((a), (b), (c), 0, 0, 0)
#define MFMA32_BF16(a, b, c) __builtin_amdgcn_mfma_f32_32x32x16_bf16((a), (b), (c), 0, 0, 0)

// exp2 via the hardware transcendental (v_exp_f32 computes 2^x).
#if __has_builtin(__builtin_amdgcn_exp2f)
#define EXP2F(x) __builtin_amdgcn_exp2f(x)
#else
#define EXP2F(x) __expf((x) * 0.6931471805599453f)
#endif

static constexpr int S = 1024;
static constexpr int HD = 64;

// ---------------- fp32 -> bf16 convert ----------------
struct ConvArgs {
  const float* src[7];
  bf16_t* dst[7];
  int n[7];
};

__global__ __launch_bounds__(256) void convert_kernel(ConvArgs a) {
  const int j = blockIdx.y;
  const float4* __restrict__ s = (const float4*)a.src[j];
  bf16x8* __restrict__ d = (bf16x8*)a.dst[j];
  const int n8 = a.n[j] >> 3;
  for (int i = blockIdx.x * blockDim.x + threadIdx.x; i < n8; i += gridDim.x * blockDim.x) {
    float4 v0 = s[2 * i];
    float4 v1 = s[2 * i + 1];
    bf16x8 o;
    o[0] = (bf16_t)v0.x; o[1] = (bf16_t)v0.y; o[2] = (bf16_t)v0.z; o[3] = (bf16_t)v0.w;
    o[4] = (bf16_t)v1.x; o[5] = (bf16_t)v1.y; o[6] = (bf16_t)v1.z; o[7] = (bf16_t)v1.w;
    d[i] = o;
  }
}

// ---------------- NT GEMM: C[m][n] = sum_k A[m][k] * B[n][k] (+bias, *scale) ----------------
// (R5 version: modes 0/1 only — the mask@V GEMM lives in the attn launch so it
// can legally read Vt, which THIS launch produces.)
struct GemmCfg {
  const bf16_t* A;
  const bf16_t* Bm;
  void* out;
  const float* bias;
  int mode;
  float scale;
};

union GemmSmem {
  struct { bf16_t A[128 * 64]; bf16_t B[128 * 64]; } ab;  // 32 KB
  bf16_t C[128 * 136];                                    // 34 KB
};

__global__ __launch_bounds__(256, 3) void gemm_nt_kernel(GemmCfg c0, GemmCfg c1, GemmCfg c2, int K) {
  GemmCfg cfg = (blockIdx.y == 0) ? c0 : (blockIdx.y == 1 ? c1 : c2);
  __shared__ GemmSmem u;
  __shared__ float bias_s[128];
  const int tid = threadIdx.x;
  const int wave = tid >> 6;
  const int lane = tid & 63;
  const int g = lane >> 4;
  const int cl = lane & 15;
  const int mq = (wave & 1) * 64;
  const int nq = (wave >> 1) * 64;

  const int xcd = blockIdx.x & 7, idx = blockIdx.x >> 3;
  int mb, nb;
  if (cfg.mode == 0) { mb = xcd * 4 + (idx & 3); nb = idx >> 2; }
  else               { nb = xcd * 4 + (idx & 3); mb = idx >> 2; }
  const int m0 = mb * 128, n0 = nb * 128;

  if (tid < 128) bias_s[tid] = cfg.bias[(cfg.mode == 0 ? n0 : m0) + tid];

  const int srow = tid >> 3;
  const int sch = (tid & 7) ^ (srow & 7);
  const bf16_t* Ag = cfg.A + (size_t)(m0 + srow) * K + sch * 8;
  const bf16_t* Bg = cfg.Bm + (size_t)(n0 + srow) * K + sch * 8;
  const int swz = cl & 7;

  floatx4 acc[4][4];
#pragma unroll
  for (int i = 0; i < 4; ++i)
#pragma unroll
    for (int j = 0; j < 4; ++j) acc[i][j] = floatx4{0.f, 0.f, 0.f, 0.f};

  const int kiters = K >> 6;
  for (int kt = 0; kt < kiters; ++kt) {
    __syncthreads();
#pragma unroll
    for (int i = 0; i < 4; ++i) {
      __builtin_amdgcn_global_load_lds((g_u32_t*)(const void*)(Ag + (size_t)(i * 32) * K),
                                       (lds_u32_t*)(void*)&u.ab.A[(i * 256 + tid) * 8], 16, 0, 0);
      __builtin_amdgcn_global_load_lds((g_u32_t*)(const void*)(Bg + (size_t)(i * 32) * K),
                                       (lds_u32_t*)(void*)&u.ab.B[(i * 256 + tid) * 8], 16, 0, 0);
    }
    Ag += 64;
    Bg += 64;
    __syncthreads();

#pragma unroll
    for (int kc = 0; kc < 2; ++kc) {
      bf16x8 af[4], bfr[4];
#pragma unroll
      for (int i = 0; i < 4; ++i)
        af[i] = *(const bf16x8*)&u.ab.A[(mq + i * 16 + cl) * 64 + ((kc * 4 + g) ^ swz) * 8];
#pragma unroll
      for (int j = 0; j < 4; ++j)
        bfr[j] = *(const bf16x8*)&u.ab.B[(nq + j * 16 + cl) * 64 + ((kc * 4 + g) ^ swz) * 8];
#pragma unroll
      for (int i = 0; i < 4; ++i)
#pragma unroll
        for (int j = 0; j < 4; ++j) acc[i][j] = MFMA_BF16(af[i], bfr[j], acc[i][j]);
    }
  }

  __syncthreads();
#pragma unroll
  for (int i = 0; i < 4; ++i)
#pragma unroll
    for (int j = 0; j < 4; ++j)
#pragma unroll
      for (int r = 0; r < 4; ++r) {
        const int ml = mq + i * 16 + g * 4 + r;
        const int nl = nq + j * 16 + cl;
        float v = (acc[i][j][r] + bias_s[cfg.mode == 0 ? nl : ml]) * cfg.scale;
        u.C[ml * 136 + nl] = (bf16_t)v;
      }
  __syncthreads();
#pragma unroll
  for (int it = 0; it < 8; ++it) {
    const int ix = it * 256 + tid;
    const int ml = ix >> 4, nc = ix & 15;
    bf16x8 val = *(const bf16x8*)&u.C[ml * 136 + nc * 8];
    const int m = m0 + ml, n = n0 + nc * 8;
    size_t addr;
    if (cfg.mode == 0)
      addr = (size_t)((m >> 10) * 16 + (n >> 6)) * 65536 + (m & 1023) * 64 + (n & 63);
    else
      addr = (size_t)((n >> 10) * 16 + (m >> 6)) * 65536 + (m & 63) * 1024 + (n & 1023);
    *(bf16x8*)&((bf16_t*)cfg.out)[addr] = val;
  }
}

// ---------------- fused attention v7 + overlapped mask@V GEMM ----------------
// Grid 768 = 512 attn blocks + 256 mask-GEMM blocks, ONE launch. Both paths
// accumulate into the zeroed f32 output with unsafeAtomicAdd (device-scope hw
// f32 add) — commutative, so no intra-launch ordering is needed. Vt/Q/K were
// produced by the PREVIOUS gemm launch, so reading them here is race-free
// (this fixes R6's same-launch producer-consumer race).
//
// Attn blocks (x < 512): R5's proven shell (8 q-tiles(128) x 64 bh, XCD=bh%8,
// 4 waves x 32 q-rows, KVBLK=128, XOR-swizzled global_load_lds staging,
// 2 barriers/tile) + R4/R5's hw-verified 32x32x16 swapped-QK^T in-register-P
// inner loop — with the entire mask path REMOVED (its 8 gather loads/tile/wave
// touched ~32 cache lines each = the R4-proven poison pattern, and 1/3 of MFMA).
// out += (exp2(S^T) / rowsum) @ V.
//
// Mask-GEMM blocks (x >= 512): mask @ concat_h(V_h) = concat_h(mask @ V_h), so
// O2 = 4 batched 1024^3 NT GEMMs with A = mask, B = Vt[b] — the proven 128x128
// GEMM structure at GEMM efficiency, overlapping attn's idle pipes.
// out += mask @ V.
__global__ __launch_bounds__(256, 2) void attn_kernel(const bf16_t* __restrict__ Q,
                                                      const bf16_t* __restrict__ Kb,
                                                      const bf16_t* __restrict__ Vt,
                                                      const bf16_t* __restrict__ Mb,
                                                      float* __restrict__ out) {
  __shared__ union {
    struct { bf16_t Ks[128 * 64]; bf16_t Vs[64 * 128]; } a;  // 32 KB (attn)
    struct { bf16_t A[128 * 64]; bf16_t B[128 * 64]; } g;    // 32 KB (gemm)
  } sm;
  const int tid = threadIdx.x;
  const int wave = tid >> 6, lane = tid & 63;

  if (blockIdx.x >= 512) {
    // ---------- mask @ V GEMM path ----------
    const int g4 = lane >> 4, cl = lane & 15;
    const int mq = (wave & 1) * 64, nq = (wave >> 1) * 64;
    const int bid = blockIdx.x - 512;        // 0..255
    const int nb = bid & 7;                  // XCD-aligned n-slab (512 % 8 == 0)
    const int mb = (bid >> 3) & 7;
    const int batch = bid >> 6;              // 0..3
    const int m0 = mb * 128, n0 = nb * 128;
    const int srow = tid >> 3, sch = (tid & 7) ^ (srow & 7);
    const bf16_t* Ag = Mb + (size_t)(m0 + srow) * 1024 + sch * 8;
    const bf16_t* Bg = Vt + (size_t)batch * (1u << 20) + (size_t)(n0 + srow) * 1024 + sch * 8;
    const int swz = cl & 7;

    floatx4 acc[4][4];
#pragma unroll
    for (int i = 0; i < 4; ++i)
#pragma unroll
      for (int j = 0; j < 4; ++j) acc[i][j] = floatx4{0.f, 0.f, 0.f, 0.f};

    for (int kt = 0; kt < 16; ++kt) {
      __syncthreads();
#pragma unroll
      for (int i = 0; i < 4; ++i) {
        __builtin_amdgcn_global_load_lds((g_u32_t*)(const void*)(Ag + (size_t)(i * 32) * 1024),
                                         (lds_u32_t*)(void*)&sm.g.A[(i * 256 + tid) * 8], 16, 0, 0);
        __builtin_amdgcn_global_load_lds((g_u32_t*)(const void*)(Bg + (size_t)(i * 32) * 1024),
                                         (lds_u32_t*)(void*)&sm.g.B[(i * 256 + tid) * 8], 16, 0, 0);
      }
      Ag += 64;
      Bg += 64;
      __syncthreads();

#pragma unroll
      for (int kc = 0; kc < 2; ++kc) {
        bf16x8 af[4], bfr[4];
#pragma unroll
        for (int i = 0; i < 4; ++i)
          af[i] = *(const bf16x8*)&sm.g.A[(mq + i * 16 + cl) * 64 + ((kc * 4 + g4) ^ swz) * 8];
#pragma unroll
        for (int j = 0; j < 4; ++j)
          bfr[j] = *(const bf16x8*)&sm.g.B[(nq + j * 16 + cl) * 64 + ((kc * 4 + g4) ^ swz) * 8];
#pragma unroll
        for (int i = 0; i < 4; ++i)
#pragma unroll
          for (int j = 0; j < 4; ++j) acc[i][j] = MFMA_BF16(af[i], bfr[j], acc[i][j]);
      }
    }

    // out[batch][m][n] += acc  (atomic: attn blocks add the softmax term)
    float* O = out + (size_t)batch * (1u << 20);
#pragma unroll
    for (int i = 0; i < 4; ++i)
#pragma unroll
      for (int j = 0; j < 4; ++j)
#pragma unroll
        for (int r = 0; r < 4; ++r) {
          const int ml = m0 + mq + i * 16 + g4 * 4 + r;
          const int nl = n0 + nq + j * 16 + cl;
          unsafeAtomicAdd(&O[(size_t)ml * 1024 + nl], acc[i][j][r]);
        }
    return;
  }

  // ---------- attention path ----------
  const int l31 = lane & 31, hi = lane >> 5;
  const int bh = blockIdx.x & 63, qt = blockIdx.x >> 6;
  const int q0w = qt * 128 + wave * 32;
  const bf16_t* Qp = Q + (size_t)bh * (S * HD);
  const bf16_t* Kp = Kb + (size_t)bh * (S * HD);
  const bf16_t* Vp = Vt + (size_t)bh * (S * HD);

  const int krow = tid >> 3, kch = (tid & 7) ^ (krow & 7);
  const int vrow = tid >> 4, vch = (tid & 15) ^ (vrow & 7);
  const int swk = l31 & 7;  // reader swizzle key: frag row & 7 == l31 & 7

  // Q B-frags (32x32x16), resident all kernel: lane holds Q[q0w+l31][kk*16+hi*8+0..7]
  bf16x8 qf[4];
#pragma unroll
  for (int kk = 0; kk < 4; ++kk)
    qf[kk] = *(const bf16x8*)&Qp[(size_t)(q0w + l31) * HD + kk * 16 + hi * 8];

  floatx16 o[2];
#pragma unroll
  for (int nt = 0; nt < 2; ++nt)
#pragma unroll
    for (int r = 0; r < 16; ++r) o[nt][r] = 0.f;
  float dsq = 0.f;

  for (int kt = 0; kt < 8; ++kt) {
    const int k0 = kt * 128;
    __syncthreads();
#pragma unroll
    for (int i = 0; i < 4; ++i)
      __builtin_amdgcn_global_load_lds(
          (g_u32_t*)(const void*)&Kp[(size_t)(k0 + i * 32 + krow) * HD + kch * 8],
          (lds_u32_t*)(void*)&sm.a.Ks[(i * 256 + tid) * 8], 16, 0, 0);
#pragma unroll
    for (int i = 0; i < 4; ++i)
      __builtin_amdgcn_global_load_lds(
          (g_u32_t*)(const void*)&Vp[(size_t)(i * 16 + vrow) * S + k0 + vch * 8],
          (lds_u32_t*)(void*)&sm.a.Vs[(i * 256 + tid) * 8], 16, 0, 0);
    __syncthreads();

    // S^T = K @ Q^T : 4 m-tiles of 32 keys, Kdim=64 (4 chunks of 16).
    floatx16 s[4];
#pragma unroll
    for (int mt = 0; mt < 4; ++mt) {
#pragma unroll
      for (int r = 0; r < 16; ++r) s[mt][r] = 0.f;
#pragma unroll
      for (int kk = 0; kk < 4; ++kk) {
        bf16x8 kf = *(const bf16x8*)&sm.a.Ks[(mt * 32 + l31) * 64 + ((kk * 2 + hi) ^ swk) * 8];
        s[mt] = MFMA32_BF16(kf, qf[kk], s[mt]);
      }
    }

    // exp2 + in-register P->A-frag conversion (pack + permlane32_swap; R4-verified).
    bf16x8 pf[8];
#pragma unroll
    for (int mt = 0; mt < 4; ++mt) {
      float e[16];
#pragma unroll
      for (int r = 0; r < 16; ++r) e[r] = EXP2F(s[mt][r]);
      float t0 = (e[0] + e[1]) + (e[2] + e[3]);
      float t1 = (e[4] + e[5]) + (e[6] + e[7]);
      float t2 = (e[8] + e[9]) + (e[10] + e[11]);
      float t3 = (e[12] + e[13]) + (e[14] + e[15]);
      dsq += (t0 + t1) + (t2 + t3);
      uint32_t c[8];
#pragma unroll
      for (int i = 0; i < 8; ++i) {
        bf16_t lo = (bf16_t)e[2 * i], hh = (bf16_t)e[2 * i + 1];
        c[i] = (uint32_t)__builtin_bit_cast(uint16_t, lo) |
               ((uint32_t)__builtin_bit_cast(uint16_t, hh) << 16);
      }
      asm volatile("v_permlane32_swap_b32 %0, %1" : "+v"(c[0]), "+v"(c[2]));
      asm volatile("v_permlane32_swap_b32 %0, %1" : "+v"(c[1]), "+v"(c[3]));
      asm volatile("v_permlane32_swap_b32 %0, %1" : "+v"(c[4]), "+v"(c[6]));
      asm volatile("v_permlane32_swap_b32 %0, %1" : "+v"(c[5]), "+v"(c[7]));
      u32x4 pe = {c[0], c[1], c[2], c[3]};
      u32x4 po = {c[4], c[5], c[6], c[7]};
      pf[2 * mt] = __builtin_bit_cast(bf16x8, pe);
      pf[2 * mt + 1] = __builtin_bit_cast(bf16x8, po);
    }

    // O += P @ V
#pragma unroll
    for (int kc = 0; kc < 8; ++kc) {
#pragma unroll
      for (int nt = 0; nt < 2; ++nt) {
        bf16x8 vf = *(const bf16x8*)&sm.a.Vs[(nt * 32 + l31) * 128 + ((kc * 2 + hi) ^ swk) * 8];
        o[nt] = MFMA32_BF16(pf[kc], vf, o[nt]);
      }
    }
  }

  // denominator: lanes l and l+32 hold complementary key-subsets for q=l31
  dsq += __shfl_xor(dsq, 32, 64);
  float dinv = 1.0f / dsq;  // valid for q = l31 on every lane

  const int b = bh >> 4, h = bh & 15;
#pragma unroll
  for (int r = 0; r < 16; ++r) {
    const int qr = (r & 3) + 8 * (r >> 2) + 4 * hi;  // C-layout row of reg r
    float dv = __builtin_bit_cast(
        float, __builtin_amdgcn_ds_bpermute(qr << 2, __builtin_bit_cast(int, dinv)));
    const int srow = q0w + qr;
#pragma unroll
    for (int nt = 0; nt < 2; ++nt) {
      const int col = nt * 32 + l31;
      unsafeAtomicAdd(&out[((size_t)b * S + srow) * 1024 + h * HD + col], o[nt][r] * dv);
    }
  }
}

extern "C" void kernel_launch(void* const* d_in, const int* in_sizes, int n_in,
                              void* d_out, int out_size, void* d_ws, size_t ws_size,
                              hipStream_t stream) {
  const float* x = (const float*)d_in[0];
  const float* y = (const float*)d_in[1];
  const float* z = (const float*)d_in[2];
  const float* mask = (const float*)d_in[3];
  const float* wq_w = (const float*)d_in[4];
  const float* wq_b = (const float*)d_in[5];
  const float* wk_w = (const float*)d_in[6];
  const float* wk_b = (const float*)d_in[7];
  const float* wv_w = (const float*)d_in[8];
  const float* wv_b = (const float*)d_in[9];

  uint8_t* ws = (uint8_t*)d_ws;
  const size_t MB = 1u << 20;
  bf16_t* Xb = (bf16_t*)(ws + 0 * MB);
  bf16_t* Yb = (bf16_t*)(ws + 8 * MB);
  bf16_t* Zb = (bf16_t*)(ws + 16 * MB);
  bf16_t* Wqb = (bf16_t*)(ws + 24 * MB);
  bf16_t* Wkb = (bf16_t*)(ws + 26 * MB);
  bf16_t* Wvb = (bf16_t*)(ws + 28 * MB);
  bf16_t* Mb = (bf16_t*)(ws + 30 * MB);
  bf16_t* Qb = (bf16_t*)(ws + 32 * MB);   // (b,h,s,hd) bf16, pre-scaled by log2e/32
  bf16_t* Kb = (bf16_t*)(ws + 40 * MB);   // (b,h,s,hd) bf16
  bf16_t* Vtb = (bf16_t*)(ws + 48 * MB);  // (b,h,hd,s) bf16

  ConvArgs ca;
  ca.src[0] = x;    ca.dst[0] = Xb;  ca.n[0] = 4 * 1024 * 1024;
  ca.src[1] = y;    ca.dst[1] = Yb;  ca.n[1] = 4 * 1024 * 1024;
  ca.src[2] = z;    ca.dst[2] = Zb;  ca.n[2] = 4 * 1024 * 1024;
  ca.src[3] = wq_w; ca.dst[3] = Wqb; ca.n[3] = 1024 * 1024;
  ca.src[4] = wk_w; ca.dst[4] = Wkb; ca.n[4] = 1024 * 1024;
  ca.src[5] = wv_w; ca.dst[5] = Wvb; ca.n[5] = 1024 * 1024;
  ca.src[6] = mask; ca.dst[6] = Mb;  ca.n[6] = 1024 * 1024;
  convert_kernel<<<dim3(512, 7), 256, 0, stream>>>(ca);

  // Q = (x@Wq^T)*log2e/32, K = y@Wk^T, Vt = Wv@z^T (transposed out)
  const float qscale = 0.0450842200277801f;  // log2(e) / 32
  GemmCfg cq{Xb, Wqb, (void*)Qb, wq_b, 0, qscale};
  GemmCfg ck{Yb, Wkb, (void*)Kb, wk_b, 0, 1.0f};
  GemmCfg cv{Wvb, Zb, (void*)Vtb, wv_b, 1, 1.0f};
  gemm_nt_kernel<<<dim3(256, 3), 256, 0, stream>>>(cq, ck, cv, 1024);

  // attn (512 blocks) + overlapped mask@V GEMM (256 blocks), both atomically
  // accumulating into the zeroed f32 output.
  attn_kernel<<<dim3(768), 256, 0, stream>>>(Qb, Kb, Vtb, Mb, (float*)d_out);
}

// Round 8
// 191.437 us; speedup vs baseline: 1.0078x; 1.0078x over previous
//
#include <hip/hip_runtime.h>
#include <hip/hip_bf16.h>
#include <cstdint>

typedef __bf16 bf16_t;
typedef __bf16 bf16x8 __attribute__((ext_vector_type(8)));
typedef __bf16 bf16x4 __attribute__((ext_vector_type(4)));
typedef float floatx4 __attribute__((ext_vector_type(4)));
typedef float floatx16 __attribute__((ext_vector_type(16)));
typedef uint32_t u32x4 __attribute__((ext_vector_type(4)));

typedef __attribute__((address_space(3))) uint32_t lds_u32_t;
typedef const __attribute__((address_space(1))) uint32_t g_u32_t;

#define MFMA_BF16(a, b, c) __builtin_amdgcn_mfma_f32_16x16x32_bf16((a), (b), (c), 0, 0, 0)
#define MFMA32_BF16(a, b, c) __builtin_amdgcn_mfma_f32_32x32x16_bf16((a), (b), (c), 0, 0, 0)

// exp2 via the hardware transcendental (v_exp_f32 computes 2^x).
#if __has_builtin(__builtin_amdgcn_exp2f)
#define EXP2F(x) __builtin_amdgcn_exp2f(x)
#else
#define EXP2F(x) __expf((x) * 0.6931471805599453f)
#endif

static constexpr int S = 1024;
static constexpr int HD = 64;

// ---------------- fp32 -> bf16 convert ----------------
struct ConvArgs {
  const float* src[7];
  bf16_t* dst[7];
  int n[7];
};

__global__ __launch_bounds__(256) void convert_kernel(ConvArgs a) {
  const int j = blockIdx.y;
  const float4* __restrict__ s = (const float4*)a.src[j];
  bf16x8* __restrict__ d = (bf16x8*)a.dst[j];
  const int n8 = a.n[j] >> 3;
  for (int i = blockIdx.x * blockDim.x + threadIdx.x; i < n8; i += gridDim.x * blockDim.x) {
    float4 v0 = s[2 * i];
    float4 v1 = s[2 * i + 1];
    bf16x8 o;
    o[0] = (bf16_t)v0.x; o[1] = (bf16_t)v0.y; o[2] = (bf16_t)v0.z; o[3] = (bf16_t)v0.w;
    o[4] = (bf16_t)v1.x; o[5] = (bf16_t)v1.y; o[6] = (bf16_t)v1.z; o[7] = (bf16_t)v1.w;
    d[i] = o;
  }
}

// ---------------- NT GEMM: C[m][n] = sum_k A[m][k] * B[n][k] ----------------
// mode 0 (Q,K: +bias,*scale, bf16 out): each XCD owns 4 mb + all nb.
// mode 1 (V: +bias, bf16 out transposed-addr): each XCD owns 4 nb + all mb.
// mode 2 (O2 = mask @ V^T, batched over 4, f32 plain stores, no bias):
//   mask@concat_h(V_h) = concat_h(mask@V_h) -> 4 NT GEMMs with B = Vt[b].
//   Launched SEPARATELY after the mode-0/1 launch so reading Vt is race-free
//   (R7's atomic same-launch overlap regressed; R6's same-launch read raced).
//   Math hw-verified by R7 (passed).
struct GemmCfg {
  const bf16_t* A;
  const bf16_t* Bm;
  void* out;
  const float* bias;
  int mode;
  float scale;
};

union GemmSmem {
  struct { bf16_t A[128 * 64]; bf16_t B[128 * 64]; } ab;  // 32 KB
  bf16_t C[128 * 136];                                    // 34 KB
};

__global__ __launch_bounds__(256, 3) void gemm_nt_kernel(GemmCfg c0, GemmCfg c1, GemmCfg c2, int K) {
  GemmCfg cfg = (blockIdx.y == 0) ? c0 : (blockIdx.y == 1 ? c1 : c2);
  __shared__ GemmSmem u;
  __shared__ float bias_s[128];
  const int tid = threadIdx.x;
  const int wave = tid >> 6;
  const int lane = tid & 63;
  const int g = lane >> 4;
  const int cl = lane & 15;
  const int mq = (wave & 1) * 64;
  const int nq = (wave >> 1) * 64;

  const int xcd = blockIdx.x & 7, idx = blockIdx.x >> 3;
  int mb, nb, batch = 0;
  if (cfg.mode == 0)      { mb = xcd * 4 + (idx & 3); nb = idx >> 2; }
  else if (cfg.mode == 1) { nb = xcd * 4 + (idx & 3); mb = idx >> 2; }
  else                    { nb = xcd; mb = idx & 7; batch = idx >> 3; }
  const int m0 = mb * 128, n0 = nb * 128;

  const bf16_t* Bbase = cfg.Bm + (size_t)batch * (1u << 20);
  if (cfg.mode != 2 && tid < 128) bias_s[tid] = cfg.bias[(cfg.mode == 0 ? n0 : m0) + tid];

  // staging: thread tid covers row (tid>>3) of each 32-row slab; it FETCHES
  // global chunk (tid&7)^(row&7) into linear LDS slot (tid&7).
  const int srow = tid >> 3;
  const int sch = (tid & 7) ^ (srow & 7);
  const bf16_t* Ag = cfg.A + (size_t)(m0 + srow) * K + sch * 8;
  const bf16_t* Bg = Bbase + (size_t)(n0 + srow) * K + sch * 8;
  const int swz = cl & 7;  // reader swizzle key (row&7 == cl&7 for 16-strided rows)

  floatx4 acc[4][4];
#pragma unroll
  for (int i = 0; i < 4; ++i)
#pragma unroll
    for (int j = 0; j < 4; ++j) acc[i][j] = floatx4{0.f, 0.f, 0.f, 0.f};

  const int kiters = K >> 6;
  for (int kt = 0; kt < kiters; ++kt) {
    __syncthreads();
#pragma unroll
    for (int i = 0; i < 4; ++i) {
      __builtin_amdgcn_global_load_lds((g_u32_t*)(const void*)(Ag + (size_t)(i * 32) * K),
                                       (lds_u32_t*)(void*)&u.ab.A[(i * 256 + tid) * 8], 16, 0, 0);
      __builtin_amdgcn_global_load_lds((g_u32_t*)(const void*)(Bg + (size_t)(i * 32) * K),
                                       (lds_u32_t*)(void*)&u.ab.B[(i * 256 + tid) * 8], 16, 0, 0);
    }
    Ag += 64;
    Bg += 64;
    __syncthreads();

#pragma unroll
    for (int kc = 0; kc < 2; ++kc) {
      bf16x8 af[4], bfr[4];
#pragma unroll
      for (int i = 0; i < 4; ++i)
        af[i] = *(const bf16x8*)&u.ab.A[(mq + i * 16 + cl) * 64 + ((kc * 4 + g) ^ swz) * 8];
#pragma unroll
      for (int j = 0; j < 4; ++j)
        bfr[j] = *(const bf16x8*)&u.ab.B[(nq + j * 16 + cl) * 64 + ((kc * 4 + g) ^ swz) * 8];
#pragma unroll
      for (int i = 0; i < 4; ++i)
#pragma unroll
        for (int j = 0; j < 4; ++j) acc[i][j] = MFMA_BF16(af[i], bfr[j], acc[i][j]);
    }
  }

  if (cfg.mode == 2) {
    // f32 plain stores: O2[batch][m][n]; lanes cl=0..15 = 64B segments.
    float* O = (float*)cfg.out + (size_t)batch * (1u << 20);
#pragma unroll
    for (int i = 0; i < 4; ++i)
#pragma unroll
      for (int j = 0; j < 4; ++j)
#pragma unroll
        for (int r = 0; r < 4; ++r) {
          const int ml = m0 + mq + i * 16 + g * 4 + r;
          const int nl = n0 + nq + j * 16 + cl;
          O[(size_t)ml * 1024 + nl] = acc[i][j][r];
        }
    return;
  }

  // epilogue: quadrants -> LDS (with bias+scale), then cooperative 16B coalesced stores
  __syncthreads();
#pragma unroll
  for (int i = 0; i < 4; ++i)
#pragma unroll
    for (int j = 0; j < 4; ++j)
#pragma unroll
      for (int r = 0; r < 4; ++r) {
        const int ml = mq + i * 16 + g * 4 + r;
        const int nl = nq + j * 16 + cl;
        float v = (acc[i][j][r] + bias_s[cfg.mode == 0 ? nl : ml]) * cfg.scale;
        u.C[ml * 136 + nl] = (bf16_t)v;
      }
  __syncthreads();
#pragma unroll
  for (int it = 0; it < 8; ++it) {
    const int ix = it * 256 + tid;
    const int ml = ix >> 4, nc = ix & 15;
    bf16x8 val = *(const bf16x8*)&u.C[ml * 136 + nc * 8];
    const int m = m0 + ml, n = n0 + nc * 8;
    size_t addr;
    if (cfg.mode == 0)
      addr = (size_t)((m >> 10) * 16 + (n >> 6)) * 65536 + (m & 1023) * 64 + (n & 63);
    else
      addr = (size_t)((n >> 10) * 16 + (m >> 6)) * 65536 + (m & 63) * 1024 + (n & 1023);
    *(bf16x8*)&((bf16_t*)cfg.out)[addr] = val;
  }
}

// ---------------- fused attention v8: no mask, double-buffered staging ----------------
// Shell: grid 512 = 8 q-tiles(128) x 64 (b,h), XCD = bh%8 (per-XCD L2 set now
// ~2MB: 8 bh x 256KB K/V — mask stream gone, which removes R2's L2-thrash
// mechanism and makes the clean T3 retest possible); 4 waves x 32 q-rows;
// KVBLK=128. K/V DOUBLE-BUFFERED (64 KB LDS, 2 blocks/CU): next tile's
// global_load_lds issued at loop top, ONE vmcnt-drain barrier per tile
// (8 drains vs 16) with the full QK+exp+PV phase hiding the staging latency.
// Inner (R4/R5 hw-verified): 32x32x16 swapped QK^T, lane holds P for q=lane&31
// (C-layout row=(r&3)+8*(r>>2)+4*hi), hw exp2 (scale pre-folded into Q),
// in-register P->A-frag via bf16 pack + permlane32_swap.
// Epilogue: out = O/rowsum + O2 (O2 = mask@V from the mode-2 GEMM), plain stores.
__global__ __launch_bounds__(256, 2) void attn_kernel(const bf16_t* __restrict__ Q,
                                                      const bf16_t* __restrict__ Kb,
                                                      const bf16_t* __restrict__ Vt,
                                                      const float* __restrict__ O2,
                                                      float* __restrict__ out) {
  __shared__ bf16_t Ks[2][128 * 64];  // 32 KB
  __shared__ bf16_t Vs[2][64 * 128];  // 32 KB
  const int tid = threadIdx.x;
  const int wave = tid >> 6, lane = tid & 63;
  const int l31 = lane & 31, hi = lane >> 5;
  const int bh = blockIdx.x & 63, qt = blockIdx.x >> 6;
  const int q0w = qt * 128 + wave * 32;
  const bf16_t* Qp = Q + (size_t)bh * (S * HD);
  const bf16_t* Kp = Kb + (size_t)bh * (S * HD);
  const bf16_t* Vp = Vt + (size_t)bh * (S * HD);

  // staging maps: thread tid fills LDS slot (i*256+tid)*16B, fetching the
  // global chunk c^(row&7) so readers find data chunk cw at slot cw^(row&7).
  const int krow = tid >> 3, kch = (tid & 7) ^ (krow & 7);
  const int vrow = tid >> 4, vch = (tid & 15) ^ (vrow & 7);
  const int swk = l31 & 7;  // reader swizzle key: frag row & 7 == l31 & 7

#define STAGE(BUF, KT)                                                                      \
  do {                                                                                      \
    const int k0s = (KT) * 128;                                                             \
    _Pragma("unroll") for (int i = 0; i < 4; ++i)                                           \
        __builtin_amdgcn_global_load_lds(                                                   \
            (g_u32_t*)(const void*)&Kp[(size_t)(k0s + i * 32 + krow) * HD + kch * 8],       \
            (lds_u32_t*)(void*)&Ks[BUF][(i * 256 + tid) * 8], 16, 0, 0);                    \
    _Pragma("unroll") for (int i = 0; i < 4; ++i)                                           \
        __builtin_amdgcn_global_load_lds(                                                   \
            (g_u32_t*)(const void*)&Vp[(size_t)(i * 16 + vrow) * S + k0s + vch * 8],        \
            (lds_u32_t*)(void*)&Vs[BUF][(i * 256 + tid) * 8], 16, 0, 0);                    \
  } while (0)

  // Q B-frags (32x32x16), resident all kernel: lane holds Q[q0w+l31][kk*16+hi*8+0..7]
  bf16x8 qf[4];
#pragma unroll
  for (int kk = 0; kk < 4; ++kk)
    qf[kk] = *(const bf16x8*)&Qp[(size_t)(q0w + l31) * HD + kk * 16 + hi * 8];

  floatx16 o[2];
#pragma unroll
  for (int nt = 0; nt < 2; ++nt)
#pragma unroll
    for (int r = 0; r < 16; ++r) o[nt][r] = 0.f;
  float dsq = 0.f;

  // prologue: stage tile 0; the barrier's implicit vmcnt(0) drains it
  STAGE(0, 0);
  __syncthreads();

  int cur = 0;
  for (int kt = 0; kt < 8; ++kt) {
    // issue NEXT tile's staging first; it flows under this tile's compute and
    // is drained by the single barrier at the bottom of the loop.
    if (kt < 7) STAGE(cur ^ 1, kt + 1);

    const bf16_t* Kc = &Ks[cur][0];
    const bf16_t* Vc = &Vs[cur][0];

    // S^T = K @ Q^T : 4 m-tiles of 32 keys, Kdim=64 (4 chunks of 16).
    floatx16 s[4];
#pragma unroll
    for (int mt = 0; mt < 4; ++mt) {
#pragma unroll
      for (int r = 0; r < 16; ++r) s[mt][r] = 0.f;
#pragma unroll
      for (int kk = 0; kk < 4; ++kk) {
        bf16x8 kf = *(const bf16x8*)&Kc[(mt * 32 + l31) * 64 + ((kk * 2 + hi) ^ swk) * 8];
        s[mt] = MFMA32_BF16(kf, qf[kk], s[mt]);
      }
    }

    // exp2 + in-register P->A-frag conversion (pack + permlane32_swap; R4-verified).
    bf16x8 pf[8];
#pragma unroll
    for (int mt = 0; mt < 4; ++mt) {
      float e[16];
#pragma unroll
      for (int r = 0; r < 16; ++r) e[r] = EXP2F(s[mt][r]);
      float t0 = (e[0] + e[1]) + (e[2] + e[3]);
      float t1 = (e[4] + e[5]) + (e[6] + e[7]);
      float t2 = (e[8] + e[9]) + (e[10] + e[11]);
      float t3 = (e[12] + e[13]) + (e[14] + e[15]);
      dsq += (t0 + t1) + (t2 + t3);
      uint32_t c[8];
#pragma unroll
      for (int i = 0; i < 8; ++i) {
        bf16_t lo = (bf16_t)e[2 * i], hh = (bf16_t)e[2 * i + 1];
        c[i] = (uint32_t)__builtin_bit_cast(uint16_t, lo) |
               ((uint32_t)__builtin_bit_cast(uint16_t, hh) << 16);
      }
      asm volatile("v_permlane32_swap_b32 %0, %1" : "+v"(c[0]), "+v"(c[2]));
      asm volatile("v_permlane32_swap_b32 %0, %1" : "+v"(c[1]), "+v"(c[3]));
      asm volatile("v_permlane32_swap_b32 %0, %1" : "+v"(c[4]), "+v"(c[6]));
      asm volatile("v_permlane32_swap_b32 %0, %1" : "+v"(c[5]), "+v"(c[7]));
      u32x4 pe = {c[0], c[1], c[2], c[3]};
      u32x4 po = {c[4], c[5], c[6], c[7]};
      pf[2 * mt] = __builtin_bit_cast(bf16x8, pe);
      pf[2 * mt + 1] = __builtin_bit_cast(bf16x8, po);
    }

    // O += P @ V
#pragma unroll
    for (int kc = 0; kc < 8; ++kc) {
#pragma unroll
      for (int nt = 0; nt < 2; ++nt) {
        bf16x8 vf = *(const bf16x8*)&Vc[(nt * 32 + l31) * 128 + ((kc * 2 + hi) ^ swk) * 8];
        o[nt] = MFMA32_BF16(pf[kc], vf, o[nt]);
      }
    }

    // one barrier per tile: drains next-tile staging (vmcnt) and fences all
    // waves' reads of buffer `cur` before iteration kt+1 overwrites it.
    __syncthreads();
    cur ^= 1;
  }
#undef STAGE

  // denominator: lanes l and l+32 hold complementary key-subsets for q=l31
  dsq += __shfl_xor(dsq, 32, 64);
  float dinv = 1.0f / dsq;  // valid for q = l31 on every lane

  const int b = bh >> 4, h = bh & 15;
  const float* O2p = O2 + ((size_t)b * S) * 1024 + h * HD;
#pragma unroll
  for (int r = 0; r < 16; ++r) {
    const int qr = (r & 3) + 8 * (r >> 2) + 4 * hi;  // C-layout row of reg r
    float dv = __builtin_bit_cast(
        float, __builtin_amdgcn_ds_bpermute(qr << 2, __builtin_bit_cast(int, dinv)));
    const int srow = q0w + qr;
#pragma unroll
    for (int nt = 0; nt < 2; ++nt) {
      const int col = nt * 32 + l31;
      out[((size_t)b * S + srow) * 1024 + h * HD + col] =
          o[nt][r] * dv + O2p[(size_t)srow * 1024 + col];
    }
  }
}

extern "C" void kernel_launch(void* const* d_in, const int* in_sizes, int n_in,
                              void* d_out, int out_size, void* d_ws, size_t ws_size,
                              hipStream_t stream) {
  const float* x = (const float*)d_in[0];
  const float* y = (const float*)d_in[1];
  const float* z = (const float*)d_in[2];
  const float* mask = (const float*)d_in[3];
  const float* wq_w = (const float*)d_in[4];
  const float* wq_b = (const float*)d_in[5];
  const float* wk_w = (const float*)d_in[6];
  const float* wk_b = (const float*)d_in[7];
  const float* wv_w = (const float*)d_in[8];
  const float* wv_b = (const float*)d_in[9];

  uint8_t* ws = (uint8_t*)d_ws;
  const size_t MB = 1u << 20;
  bf16_t* Xb = (bf16_t*)(ws + 0 * MB);
  bf16_t* Yb = (bf16_t*)(ws + 8 * MB);
  bf16_t* Zb = (bf16_t*)(ws + 16 * MB);
  bf16_t* Wqb = (bf16_t*)(ws + 24 * MB);
  bf16_t* Wkb = (bf16_t*)(ws + 26 * MB);
  bf16_t* Wvb = (bf16_t*)(ws + 28 * MB);
  bf16_t* Mb = (bf16_t*)(ws + 30 * MB);
  bf16_t* Qb = (bf16_t*)(ws + 32 * MB);   // (b,h,s,hd) bf16, pre-scaled by log2e/32
  bf16_t* Kb = (bf16_t*)(ws + 40 * MB);   // (b,h,s,hd) bf16
  bf16_t* Vtb = (bf16_t*)(ws + 48 * MB);  // (b,h,hd,s) bf16
  float* O2f = (float*)(ws + 56 * MB);    // (b,s,d) f32 = mask @ V

  ConvArgs ca;
  ca.src[0] = x;    ca.dst[0] = Xb;  ca.n[0] = 4 * 1024 * 1024;
  ca.src[1] = y;    ca.dst[1] = Yb;  ca.n[1] = 4 * 1024 * 1024;
  ca.src[2] = z;    ca.dst[2] = Zb;  ca.n[2] = 4 * 1024 * 1024;
  ca.src[3] = wq_w; ca.dst[3] = Wqb; ca.n[3] = 1024 * 1024;
  ca.src[4] = wk_w; ca.dst[4] = Wkb; ca.n[4] = 1024 * 1024;
  ca.src[5] = wv_w; ca.dst[5] = Wvb; ca.n[5] = 1024 * 1024;
  ca.src[6] = mask; ca.dst[6] = Mb;  ca.n[6] = 1024 * 1024;
  convert_kernel<<<dim3(512, 7), 256, 0, stream>>>(ca);

  // Launch 1: Q = (x@Wq^T)*log2e/32, K = y@Wk^T, Vt = Wv@z^T (transposed out)
  const float qscale = 0.0450842200277801f;  // log2(e) / 32
  GemmCfg cq{Xb, Wqb, (void*)Qb, wq_b, 0, qscale};
  GemmCfg ck{Yb, Wkb, (void*)Kb, wk_b, 0, 1.0f};
  GemmCfg cv{Wvb, Zb, (void*)Vtb, wv_b, 1, 1.0f};
  gemm_nt_kernel<<<dim3(256, 3), 256, 0, stream>>>(cq, ck, cv, 1024);

  // Launch 2: O2[b] = mask @ V[b] (mode 2; reads Vtb from launch 1 -> race-free)
  GemmCfg cm{Mb, Vtb, (void*)O2f, wq_b, 2, 1.0f};
  gemm_nt_kernel<<<dim3(256, 1), 256, 0, stream>>>(cm, cm, cm, 1024);

  // Launch 3: attention (no mask path), epilogue adds O2
  attn_kernel<<<dim3(512), 256, 0, stream>>>(Qb, Kb, Vtb, O2f, (float*)d_out);
}